// Round 1
// baseline (53.717 us; speedup 1.0000x reference)
//
#include <hip/hip_runtime.h>
#include <hip/hip_bf16.h>

#define MROWS 65536
#define DD 768
#define HH 64

typedef __attribute__((ext_vector_type(8))) short short8;
typedef __attribute__((ext_vector_type(4))) float f32x4;

// f32 -> bf16 round-to-nearest-even (bit trick; NaN irrelevant for this data)
__device__ inline unsigned short f2bf(float x) {
    union { float f; unsigned u; } v; v.f = x;
    unsigned r = v.u + 0x7fffu + ((v.u >> 16) & 1u);
    return (unsigned short)(r >> 16);
}

// identity buckets <=4, floor(log2)+3 above, clamped [0,9] (exact int version)
__device__ inline int bucket(int c) {
    int idx = (c <= 4) ? c : (34 - __clz(c));   // 31 - clz + 3
    idx = idx < 0 ? 0 : idx;
    return idx > 9 ? 9 : idx;
}

// ws layout:
//   Wf    : bf16[24][4][64][8]  = 49152 ushort  (98304 B)  -- W_eff in B-fragment order
//   constv: f32[64]             @ 98304          -- b1 + ment @ W1[768:1536]
//   dlut  : f32[10][64]         @ 98560          -- dist_table @ W1[2304:2324]
//   clut  : f32[10][64]         @ 101120         -- counter_table @ W1[2324:2344]
__global__ void precompute_kernel(const float* __restrict__ ment,
                                  const float* __restrict__ dist_t,
                                  const float* __restrict__ cnt_t,
                                  const float* __restrict__ W1,
                                  const float* __restrict__ b1,
                                  unsigned short* __restrict__ Wf,
                                  float* __restrict__ constv,
                                  float* __restrict__ dlut,
                                  float* __restrict__ clut) {
    __shared__ float red[256];
    int b = blockIdx.x;
    if (b < 24) {
        // pack W_eff for k-step s = b: W_eff[d][h] = W1[d][h] + ment[d]*W1[1536+d][h]
        int s = b;
        for (int e = threadIdx.x; e < 2048; e += blockDim.x) {
            int t    = e >> 9;          // n-tile 0..3
            int lane = (e >> 3) & 63;
            int j    = e & 7;
            int d = s * 32 + ((lane >> 4) * 8 + j);
            int h = t * 16 + (lane & 15);
            float v = W1[d * HH + h] + ment[d] * W1[(1536 + d) * HH + h];
            Wf[(size_t)((s * 4 + t) * 64 + lane) * 8 + j] = f2bf(v);
        }
    } else if (b == 24) {
        // constv[h] = b1[h] + sum_d ment[d] * W1[768+d][h]   (256-way parallel + LDS reduce)
        int h = threadIdx.x & 63;
        int chunk = threadIdx.x >> 6;            // 0..3, 192 d's each
        float acc = 0.f;
        #pragma unroll 8
        for (int d = chunk * 192; d < chunk * 192 + 192; ++d)
            acc += ment[d] * W1[(768 + d) * HH + h];
        red[threadIdx.x] = acc;
        __syncthreads();
        if (chunk == 0)
            constv[h] = b1[h] + red[h] + red[64 + h] + red[128 + h] + red[192 + h];
    } else if (b == 25) {
        for (int e = threadIdx.x; e < 640; e += blockDim.x) {
            int tt = e >> 6, h = e & 63;
            float a = 0.f;
            #pragma unroll
            for (int k = 0; k < 20; ++k)
                a += dist_t[tt * 20 + k] * W1[(2304 + k) * HH + h];
            dlut[e] = a;
        }
    } else if (b == 26) {
        for (int e = threadIdx.x; e < 640; e += blockDim.x) {
            int tt = e >> 6, h = e & 63;
            float a = 0.f;
            #pragma unroll
            for (int k = 0; k < 20; ++k)
                a += cnt_t[tt * 20 + k] * W1[(2324 + k) * HH + h];
            clut[e] = a;
        }
    }
}

// 4 waves/block, each wave computes 16 rows x 64 h via mfma_f32_16x16x32_bf16.
// A loaded straight from global (f32 -> bf16 in-register), B from pre-packed ws.
__global__ __launch_bounds__(256) void score_kernel(
    const float* __restrict__ mem,
    const unsigned short* __restrict__ Wf,
    const float* __restrict__ constv,
    const float* __restrict__ dlut,
    const float* __restrict__ clut,
    const float* __restrict__ W2,
    const float* __restrict__ b2p,
    const int* __restrict__ entc,
    const int* __restrict__ lms,
    const int* __restrict__ msp,
    float* __restrict__ out) {

    int wave = threadIdx.x >> 6;
    int lane = threadIdx.x & 63;
    int g  = lane >> 4;     // 0..3
    int c0 = lane & 15;     // 0..15
    int row0 = blockIdx.x * 64 + wave * 16;     // wave's first row

    if (blockIdx.x == 0 && threadIdx.x == 0) out[MROWS] = 0.0f;  // dummy new-cluster score

    // A fragment source: row = row0 + c0, k = s*32 + g*8 + j
    const float* arow = mem + (size_t)(row0 + c0) * DD + g * 8;

    f32x4 acc0 = {0.f,0.f,0.f,0.f}, acc1 = {0.f,0.f,0.f,0.f};
    f32x4 acc2 = {0.f,0.f,0.f,0.f}, acc3 = {0.f,0.f,0.f,0.f};

    #pragma unroll 4
    for (int s = 0; s < 24; ++s) {
        f32x4 a0 = *(const f32x4*)(arow + s * 32);
        f32x4 a1 = *(const f32x4*)(arow + s * 32 + 4);
        short8 af;
        af[0] = (short)f2bf(a0[0]); af[1] = (short)f2bf(a0[1]);
        af[2] = (short)f2bf(a0[2]); af[3] = (short)f2bf(a0[3]);
        af[4] = (short)f2bf(a1[0]); af[5] = (short)f2bf(a1[1]);
        af[6] = (short)f2bf(a1[2]); af[7] = (short)f2bf(a1[3]);

        const unsigned short* bp = Wf + (size_t)s * 2048 + lane * 8;
        short8 bf0 = *(const short8*)(bp);
        short8 bf1 = *(const short8*)(bp + 512);
        short8 bf2 = *(const short8*)(bp + 1024);
        short8 bf3 = *(const short8*)(bp + 1536);

        acc0 = __builtin_amdgcn_mfma_f32_16x16x32_bf16(af, bf0, acc0, 0, 0, 0);
        acc1 = __builtin_amdgcn_mfma_f32_16x16x32_bf16(af, bf1, acc1, 0, 0, 0);
        acc2 = __builtin_amdgcn_mfma_f32_16x16x32_bf16(af, bf2, acc2, 0, 0, 0);
        acc3 = __builtin_amdgcn_mfma_f32_16x16x32_bf16(af, bf3, acc3, 0, 0, 0);
    }

    // Epilogue. D layout (m89): col = lane&15 (h-tile col), row = g*4 + reg.
    int ms  = msp[0];
    float b2v = b2p[0];
    float cv[4], w2[4];
    #pragma unroll
    for (int t = 0; t < 4; ++t) {
        cv[t] = constv[t * 16 + c0];
        w2[t] = W2[t * 16 + c0];
    }

    #pragma unroll
    for (int i = 0; i < 4; ++i) {
        int row = row0 + g * 4 + i;
        int c    = entc[row];
        int dist = ms - lms[row];
        int db = bucket(dist);
        int cb = bucket(c);
        float part = 0.f;
        #pragma unroll
        for (int t = 0; t < 4; ++t) {
            float a = (t == 0) ? acc0[i] : (t == 1) ? acc1[i] : (t == 2) ? acc2[i] : acc3[i];
            int hc = t * 16 + c0;
            float h = a + cv[t] + dlut[db * 64 + hc] + clut[cb * 64 + hc];
            h = fmaxf(h, 0.f);
            part += h * w2[t];
        }
        // reduce across the 16 lanes of this group (lanes share g)
        part += __shfl_xor(part, 8, 64);
        part += __shfl_xor(part, 4, 64);
        part += __shfl_xor(part, 2, 64);
        part += __shfl_xor(part, 1, 64);
        if (c0 == 0)
            out[row] = (c > 0) ? (part + b2v) : -10000.0f;
    }
}

extern "C" void kernel_launch(void* const* d_in, const int* in_sizes, int n_in,
                              void* d_out, int out_size, void* d_ws, size_t ws_size,
                              hipStream_t stream) {
    const float* ment   = (const float*)d_in[0];
    const float* mem    = (const float*)d_in[1];
    const float* dist_t = (const float*)d_in[2];
    const float* cnt_t  = (const float*)d_in[3];
    const float* W1     = (const float*)d_in[4];
    const float* b1     = (const float*)d_in[5];
    const float* W2     = (const float*)d_in[6];
    const float* b2     = (const float*)d_in[7];
    const int*   entc   = (const int*)d_in[8];
    const int*   lmsp   = (const int*)d_in[9];
    const int*   msp    = (const int*)d_in[10];

    unsigned short* Wf = (unsigned short*)d_ws;
    float* constv = (float*)((char*)d_ws + 98304);
    float* dlut   = constv + 64;
    float* clut   = dlut + 640;

    precompute_kernel<<<27, 256, 0, stream>>>(ment, dist_t, cnt_t, W1, b1, Wf, constv, dlut, clut);
    score_kernel<<<1024, 256, 0, stream>>>(mem, Wf, constv, dlut, clut, W2, b2,
                                           entc, lmsp, msp, (float*)d_out);
}